// Round 9
// baseline (147.440 us; speedup 1.0000x reference)
//
#include <hip/hip_runtime.h>
#include <stdint.h>

#define NB 8
#define NA 32
#define NS 16
#define KE 18750        // floats per emotion row
#define K3 43500        // floats per 3dmm row
#define KH_E 9375       // float2 per emotion row
#define KH_3 21750      // float2 per 3dmm row
#define ND3 58
#define NKL 262144      // 4*8*16*512

#define CHUNK_F2 256    // float2 per block-chunk (64 per wave)
#define NCH_E 37        // ceil(9375/256)
#define NCH_D 85        // ceil(21750/256)
#define E_SLABS 4
#define D_SLABS 8
#define SLABS 12
#define COST_BLOCKS (NB * 8 * SLABS)   // 768
#define KL_BLOCKS 64
#define KL_PER_THR (NKL / (KL_BLOCKS * 256))   // 16

#define SW_1 0.0050637127f    // sqrt(1/39000)
#define SW_2 0.0471404521f    // sqrt(10/4500)
#define W_E  (1.0f / 18750.0f)

// ---------------------------------------------------------------------------
// blocks [0, KL_BLOCKS): KL partial sums -> atomic klsum
// blocks [KL_BLOCKS, +COST_BLOCKS): pairwise weighted-SSD via global_load_lds
//   staging into wave-private double-buffered LDS; counted vmcnt(8); no
//   barriers in the k-loop. 8x8 (s,a) register tile per lane, 1 f2-col/lane.
// ---------------------------------------------------------------------------
__global__ __launch_bounds__(256, 2) void fused_kernel(
    const float* __restrict__ ge, const float* __restrict__ g3,
    const float* __restrict__ pe, const float* __restrict__ p3,
    const float* __restrict__ mu, const float* __restrict__ sc,
    float* __restrict__ cost, float* __restrict__ klsum)
{
    __shared__ float lds[4][2][16][128];   // 64 KB: [wave][buf][row][f2*2 floats]
    float* red = &lds[0][0][0][0];         // epilogue reuse (after barrier)

    const int blk = blockIdx.x;
    const int tid = threadIdx.x;
    const int w   = tid >> 6;
    const int l   = tid & 63;

    if (blk < KL_BLOCKS) {
        // ---------------- KL part ----------------
        float ks = 0.f;
        #pragma unroll
        for (int it = 0; it < KL_PER_THR; ++it) {
            const int i = blk * (256 * KL_PER_THR) + it * 256 + tid;
            const float m = mu[i], sg = sc[i];
            ks += 0.5f * (sg * sg + m * m - 1.0f) - logf(sg);
        }
        #pragma unroll
        for (int o = 32; o > 0; o >>= 1) ks += __shfl_xor(ks, o);
        if (l == 0) red[w] = ks;
        __syncthreads();
        if (tid == 0)
            atomicAdd(klsum, red[0] + red[1] + red[2] + red[3]);
        return;
    }

    // ---------------- pairwise cost part ----------------
    const int cblk = blk - KL_BLOCKS;
    const int b    = cblk / (8 * SLABS);
    const int rem  = cblk % (8 * SLABS);
    const int pos  = rem / SLABS;
    const int slab = rem % SLABS;
    const int s0   = (pos >> 2) * 8;
    const int a0   = (pos & 3) * 8;

    const bool isE = slab < E_SLABS;
    const int  KF  = isE ? KE : K3;
    const int  KH  = isE ? KH_E : KH_3;
    int clo, chi;
    if (isE) { clo = slab * NCH_E / E_SLABS; chi = (slab + 1) * NCH_E / E_SLABS; }
    else {
        const int ds = slab - E_SLABS;
        clo = ds * NCH_D / D_SLABS; chi = (ds + 1) * NCH_D / D_SLABS;
    }

    const float* __restrict__ Pr = isE ? pe + (size_t)(b * NS + s0) * KE
                                       : p3 + (size_t)(b * NS + s0) * K3;
    const float* __restrict__ Gr = isE ? ge + (size_t)(b * NA + a0) * KE
                                       : g3 + (size_t)(b * NA + a0) * K3;

    float* wb0 = &lds[w][0][0][0];
    float* wb1 = &lds[w][1][0][0];

    float acc[64];
    #pragma unroll
    for (int i = 0; i < 64; ++i) acc[i] = 0.f;

    // stage chunk c into wave buffer wb: 8 x global_load_lds, 16B/lane.
    // inst t covers rows {2t,2t+1} (t<4: P rows 0..7; t>=4: G rows 0..7).
    // lane l -> row 2t+(l>>5), f2 cols (l&31)*2 .. +1. Dest is lane-linear.
    const int rsel = l >> 5;
    const int coff = (l & 31) * 2;
    auto STAGE = [&](int c, float* wb) {
        int f2 = c * CHUNK_F2 + w * 64 + coff;
        f2 = (f2 <= KH - 2) ? f2 : (KH - 2);          // clamp in-row (valid data)
        #pragma unroll
        for (int t = 0; t < 8; ++t) {
            const float* src = (t < 4)
                ? Pr + (size_t)(2 * t + rsel) * KF + 2 * f2
                : Gr + (size_t)(2 * (t - 4) + rsel) * KF + 2 * f2;
            __builtin_amdgcn_global_load_lds(
                (const __attribute__((address_space(1))) uint32_t*)src,
                (__attribute__((address_space(3))) uint32_t*)(wb + t * 256),
                16, 0, 0);
        }
    };

    int col = (2 * (clo * CHUNK_F2 + w * 64 + l)) % ND3;  // D-branch col tracker

    STAGE(clo, (clo & 1) ? wb1 : wb0);

    if (isE) {
        #pragma unroll 1
        for (int c = clo; c < chi - 1; ++c) {
            STAGE(c + 1, ((c + 1) & 1) ? wb1 : wb0);
            asm volatile("s_waitcnt vmcnt(8)" ::: "memory");
            const float* wb = (c & 1) ? wb1 : wb0;
            float2 p[8], g[8];
            #pragma unroll
            for (int i = 0; i < 8; ++i) p[i] = *(const float2*)(wb + i * 128 + 2 * l);
            #pragma unroll
            for (int j = 0; j < 8; ++j) g[j] = *(const float2*)(wb + (8 + j) * 128 + 2 * l);
            #pragma unroll
            for (int i = 0; i < 8; ++i)
                #pragma unroll
                for (int j = 0; j < 8; ++j) {
                    const float d0 = p[i].x - g[j].x;
                    const float d1 = p[i].y - g[j].y;
                    float t = fmaf(d0, d0, acc[i * 8 + j]);
                    acc[i * 8 + j] = fmaf(d1, d1, t);
                }
        }
    } else {
        #pragma unroll 1
        for (int c = clo; c < chi - 1; ++c) {
            STAGE(c + 1, ((c + 1) & 1) ? wb1 : wb0);
            asm volatile("s_waitcnt vmcnt(8)" ::: "memory");
            const float* wb = (c & 1) ? wb1 : wb0;
            const float sw = (col < 52) ? SW_1 : SW_2;   // both f2 comps same side
            col += 48; if (col >= ND3) col -= ND3;       // advance by 512 % 58
            float2 p[8], g[8];
            #pragma unroll
            for (int i = 0; i < 8; ++i) p[i] = *(const float2*)(wb + i * 128 + 2 * l);
            #pragma unroll
            for (int j = 0; j < 8; ++j) g[j] = *(const float2*)(wb + (8 + j) * 128 + 2 * l);
            #pragma unroll
            for (int i = 0; i < 8; ++i) { p[i].x *= sw; p[i].y *= sw; }
            #pragma unroll
            for (int j = 0; j < 8; ++j) { g[j].x *= sw; g[j].y *= sw; }
            #pragma unroll
            for (int i = 0; i < 8; ++i)
                #pragma unroll
                for (int j = 0; j < 8; ++j) {
                    const float d0 = p[i].x - g[j].x;
                    const float d1 = p[i].y - g[j].y;
                    float t = fmaf(d0, d0, acc[i * 8 + j]);
                    acc[i * 8 + j] = fmaf(d1, d1, t);
                }
        }
    }

    // ---- peeled tail chunk (chi-1): per-lane weight, 0 for OOB lanes ----
    {
        asm volatile("s_waitcnt vmcnt(0)" ::: "memory");
        const int c = chi - 1;
        const float* wb = (c & 1) ? wb1 : wb0;
        const int fi = c * CHUNK_F2 + w * 64 + l;
        float wl;
        if (isE) wl = (fi < KH) ? 1.f : 0.f;
        else     wl = (fi < KH) ? ((col < 52) ? SW_1 : SW_2) : 0.f;
        float2 p[8], g[8];
        #pragma unroll
        for (int i = 0; i < 8; ++i) p[i] = *(const float2*)(wb + i * 128 + 2 * l);
        #pragma unroll
        for (int j = 0; j < 8; ++j) g[j] = *(const float2*)(wb + (8 + j) * 128 + 2 * l);
        #pragma unroll
        for (int i = 0; i < 8; ++i) { p[i].x *= wl; p[i].y *= wl; }
        #pragma unroll
        for (int j = 0; j < 8; ++j) { g[j].x *= wl; g[j].y *= wl; }
        #pragma unroll
        for (int i = 0; i < 8; ++i)
            #pragma unroll
            for (int j = 0; j < 8; ++j) {
                const float d0 = p[i].x - g[j].x;
                const float d1 = p[i].y - g[j].y;
                float t = fmaf(d0, d0, acc[i * 8 + j]);
                acc[i * 8 + j] = fmaf(d1, d1, t);
            }
    }

    // ---- cross reduction: value-splitting butterfly (63 shfl+add) ----
    int n = 64;
    #pragma unroll
    for (int step = 0; step < 6; ++step) {
        const int o = 1 << step;
        const bool hi = (l & o) != 0;
        const int h = n >> 1;
        #pragma unroll
        for (int m = 0; m < h; ++m) {
            const float send = hi ? acc[m] : acc[m + h];
            const float recv = __shfl_xor(send, o);
            acc[m] = (hi ? acc[m + h] : acc[m]) + recv;
        }
        n = h;
    }

    __syncthreads();                       // waves done with their buffers
    red[w * 64 + (__brev((unsigned)l) >> 26)] = acc[0];
    __syncthreads();
    if (tid < 64) {
        float v = red[0 * 64 + tid] + red[1 * 64 + tid]
                + red[2 * 64 + tid] + red[3 * 64 + tid];
        if (isE) v *= W_E;
        const int i = tid >> 3, j = tid & 7;
        atomicAdd(&cost[b * (NS * NA) + (s0 + i) * NA + (a0 + j)], v);
    }
}

// 1 block x 128 threads: thread t = (b,s); min over a, mean, add KL.
__global__ __launch_bounds__(128) void finalize_kernel(
    const float* __restrict__ cost, const float* __restrict__ klsum,
    float* __restrict__ out)
{
    const int t = threadIdx.x;
    const float4* row = (const float4*)(cost + t * NA);
    float mn = 1e30f;
    #pragma unroll
    for (int q = 0; q < 8; ++q) {
        const float4 v = row[q];
        mn = fminf(mn, fminf(fminf(v.x, v.y), fminf(v.z, v.w)));
    }
    #pragma unroll
    for (int o = 32; o > 0; o >>= 1) mn += __shfl_xor(mn, o);
    __shared__ float r2[2];
    if ((t & 63) == 0) r2[t >> 6] = mn;
    __syncthreads();
    if (t == 0) {
        const float rec = (r2[0] + r2[1]) * (1.0f / (NB * NS));
        const float kld = klsum[0] * (1.0f / (float)NKL);
        out[0] = fmaf(0.0002f, kld, rec);
        out[1] = rec;
        out[2] = kld;
    }
}

extern "C" void kernel_launch(void* const* d_in, const int* in_sizes, int n_in,
                              void* d_out, int out_size, void* d_ws, size_t ws_size,
                              hipStream_t stream)
{
    const float* ge = (const float*)d_in[0];
    const float* g3 = (const float*)d_in[1];
    const float* pe = (const float*)d_in[2];
    const float* p3 = (const float*)d_in[3];
    const float* mu = (const float*)d_in[4];
    const float* sc = (const float*)d_in[5];

    float* cost  = (float*)d_ws;            // 4096 floats
    float* klsum = cost + NB * NS * NA;     // 1 float

    hipMemsetAsync(d_ws, 0, (NB * NS * NA + 1) * sizeof(float), stream);

    fused_kernel<<<COST_BLOCKS + KL_BLOCKS, 256, 0, stream>>>(
        ge, g3, pe, p3, mu, sc, cost, klsum);
    finalize_kernel<<<1, 128, 0, stream>>>(cost, klsum, (float*)d_out);
}